// Round 5
// baseline (674.435 us; speedup 1.0000x reference)
//
#include <hip/hip_runtime.h>
#include <stdint.h>

#define NB 64
#define NH 32
#define KCTX 4096
#define HID 7168
#define QLORA 1536
#define KVL 512
#define DTOT 576
#define NSPLIT 8
#define SM_SCALE 0.07216878364870323f  // 1/sqrt(192)
#define NEGINF (-3.0e38f)

typedef __attribute__((ext_vector_type(4))) float f32x4;
typedef __attribute__((ext_vector_type(8))) __bf16 bf16x8;

static __device__ __forceinline__ unsigned short f2bf(float f){
    union{__bf16 h; unsigned short s;} x; x.h = (__bf16)f; return x.s;
}
static __device__ __forceinline__ float bf2f(unsigned short h){
    union{unsigned i;float f;}x; x.i=((unsigned)h)<<16; return x.f;
}
static __device__ __forceinline__ unsigned pack2(float a, float b){
    union{__bf16 h[2]; unsigned u;} x; x.h[0]=(__bf16)a; x.h[1]=(__bf16)b; return x.u;
}

// ---------- pack A[64][K] fp32 -> frag-ready bf16 hi/lo words: word idx = (k>>3)*64+m
__global__ __launch_bounds__(256) void pack_a(const float* __restrict__ A,
        unsigned short* __restrict__ Hi, unsigned short* __restrict__ Lo, int K)
{
    int idx = blockIdx.x*256 + threadIdx.x;   // word index over 64*K/8
    int m = idx & 63, kb = idx >> 6;
    const float* src = A + (size_t)m*K + kb*8;
    float v[8];
    *(float4*)(v)   = *(const float4*)(src);
    *(float4*)(v+4) = *(const float4*)(src+4);
    unsigned short h[8], l[8];
#pragma unroll
    for (int j=0;j<8;++j){
        h[j] = f2bf(v[j]);
        l[j] = f2bf(v[j] - bf2f(h[j]));
    }
    uint4 uh, ul;
    uh.x=(unsigned)h[0]|((unsigned)h[1]<<16); uh.y=(unsigned)h[2]|((unsigned)h[3]<<16);
    uh.z=(unsigned)h[4]|((unsigned)h[5]<<16); uh.w=(unsigned)h[6]|((unsigned)h[7]<<16);
    ul.x=(unsigned)l[0]|((unsigned)l[1]<<16); ul.y=(unsigned)l[2]|((unsigned)l[3]<<16);
    ul.z=(unsigned)l[4]|((unsigned)l[5]<<16); ul.w=(unsigned)l[6]|((unsigned)l[7]<<16);
    *(uint4*)(Hi + (size_t)idx*8) = uh;
    *(uint4*)(Lo + (size_t)idx*8) = ul;
}

// ---------- MFMA skinny GEMM, double-buffered LDS, 1 barrier/step
__global__ __launch_bounds__(256) void gemm_mfma(
        const unsigned short* __restrict__ Ahi, const unsigned short* __restrict__ Alo,
        const float* __restrict__ Wm, float* __restrict__ P, int N, int ksteps)
{
    __shared__ unsigned short Ah[2][2048], Al[2][2048], Bh[2][2048], Bl[2][2048];
    const int tid = threadIdx.x;
    const int w = tid>>6, l = tid&63, lm = l&15, lg = l>>4;
    const int n0 = blockIdx.x*64;
    const int s  = blockIdx.y;
    const int mn = tid&63, ks = tid>>6;            // staging role
    const int widx = ((mn>>4)*64 + ks*16 + (mn&15));

    f32x4 acc[4];
#pragma unroll
    for (int i=0;i<4;++i){ acc[i][0]=0.f; acc[i][1]=0.f; acc[i][2]=0.f; acc[i][3]=0.f; }

    uint4 ah4, al4; float wv[8];
    auto load_raw = [&](int t){
        const int k0 = (s*ksteps + t)*32;
        size_t gidx = (size_t)((k0>>3) + ks)*64 + mn;
        ah4 = *(const uint4*)(Ahi + gidx*8);
        al4 = *(const uint4*)(Alo + gidx*8);
        const float* wp = Wm + (size_t)(k0 + ks*8)*N + n0 + mn;
#pragma unroll
        for (int j=0;j<8;++j) wv[j] = wp[(size_t)j*N];
    };
    auto cvt_write = [&](int buf){
        unsigned short h[8], lo[8];
#pragma unroll
        for (int j=0;j<8;++j){
            h[j]  = f2bf(wv[j]);
            lo[j] = f2bf(wv[j] - bf2f(h[j]));
        }
        uint4 bh4, bl4;
        bh4.x=(unsigned)h[0]|((unsigned)h[1]<<16); bh4.y=(unsigned)h[2]|((unsigned)h[3]<<16);
        bh4.z=(unsigned)h[4]|((unsigned)h[5]<<16); bh4.w=(unsigned)h[6]|((unsigned)h[7]<<16);
        bl4.x=(unsigned)lo[0]|((unsigned)lo[1]<<16); bl4.y=(unsigned)lo[2]|((unsigned)lo[3]<<16);
        bl4.z=(unsigned)lo[4]|((unsigned)lo[5]<<16); bl4.w=(unsigned)lo[6]|((unsigned)lo[7]<<16);
        *(uint4*)(&Ah[buf][widx*8]) = ah4;
        *(uint4*)(&Al[buf][widx*8]) = al4;
        *(uint4*)(&Bh[buf][widx*8]) = bh4;
        *(uint4*)(&Bl[buf][widx*8]) = bl4;
    };

    load_raw(0);
    for (int t=0; t<ksteps; ++t){
        const int buf = t&1;
        cvt_write(buf);
        __syncthreads();
        if (t+1 < ksteps) load_raw(t+1);   // issued after barrier: never barrier-drained
        const int fa = (w*64 + lg*16 + lm)*8;
        bf16x8 fah = *(const bf16x8*)(&Ah[buf][fa]);
        bf16x8 fal = *(const bf16x8*)(&Al[buf][fa]);
#pragma unroll
        for (int nt=0;nt<4;++nt){
            const int fb = (nt*64 + lg*16 + lm)*8;
            bf16x8 fbh = *(const bf16x8*)(&Bh[buf][fb]);
            bf16x8 fbl = *(const bf16x8*)(&Bl[buf][fb]);
            acc[nt] = __builtin_amdgcn_mfma_f32_16x16x32_bf16(fah, fbh, acc[nt], 0,0,0);
            acc[nt] = __builtin_amdgcn_mfma_f32_16x16x32_bf16(fal, fbh, acc[nt], 0,0,0);
            acc[nt] = __builtin_amdgcn_mfma_f32_16x16x32_bf16(fah, fbl, acc[nt], 0,0,0);
        }
    }
#pragma unroll
    for (int nt=0;nt<4;++nt){
        int n = n0 + nt*16 + lm;
#pragma unroll
        for (int r=0;r<4;++r){
            int m = w*16 + lg*4 + r;
            P[((size_t)s*64 + m)*N + n] = acc[nt][r];
        }
    }
}

// ---------- reduce S partials + rmsnorm -> q_c[64][1536]
__global__ __launch_bounds__(256) void reduce_rms_qc(const float* __restrict__ P,
        const float* __restrict__ w, float* __restrict__ out, int S)
{
    const int b = blockIdx.x, t = threadIdx.x;
    float v[6]; float ss = 0.f;
#pragma unroll
    for (int j=0;j<6;++j){
        int n = j*256 + t;
        float s = 0.f;
        for (int sp=0; sp<S; ++sp) s += P[((size_t)sp*64+b)*1536 + n];
        v[j] = s; ss += s*s;
    }
    __shared__ float red[4];
#pragma unroll
    for (int off=32; off>=1; off>>=1) ss += __shfl_xor(ss, off, 64);
    if ((t&63)==0) red[t>>6] = ss;
    __syncthreads();
    float tot = red[0]+red[1]+red[2]+red[3];
    float rs = rsqrtf(tot/1536.f + 1e-6f);
#pragma unroll
    for (int j=0;j<6;++j){
        int n = j*256+t;
        out[(size_t)b*1536 + n] = v[j]*rs*w[n];
    }
}

// ---------- generic partial reduce
__global__ __launch_bounds__(256) void reduce_sum(const float* __restrict__ P,
        float* __restrict__ out, int S, int N)
{
    int i = blockIdx.x*256 + threadIdx.x;
    int b = i / N, n = i - b*N;
    float s = 0.f;
    for (int sp=0; sp<S; ++sp) s += P[((size_t)sp*64+b)*N + n];
    out[i] = s;
}

// ---------- reduce ckv partials + rmsnorm(512) + rope(last 64) -> latent[64][576]
__global__ __launch_bounds__(256) void reduce_kv_rope(const float* __restrict__ P,
        const float* __restrict__ w, const float* __restrict__ cosb, const float* __restrict__ sinb,
        float* __restrict__ latent, int S)
{
    const int b = blockIdx.x, t = threadIdx.x;
    __shared__ float vals[576];
    __shared__ float red[4];
    float ss = 0.f;
    for (int j=0;j<3;++j){
        int n = j*256+t;
        if (n < 576){
            float s=0.f;
            for (int sp=0;sp<S;++sp) s += P[((size_t)sp*64+b)*576 + n];
            vals[n]=s;
            if (n<512) ss += s*s;
        }
    }
#pragma unroll
    for (int off=32; off>=1; off>>=1) ss += __shfl_xor(ss, off, 64);
    if ((t&63)==0) red[t>>6]=ss;
    __syncthreads();
    float tot = red[0]+red[1]+red[2]+red[3];
    float rs = rsqrtf(tot/512.f + 1e-6f);
    for (int j=0;j<3;++j){
        int n = j*256+t;
        if (n<576){
            float o;
            if (n < 512) o = vals[n]*rs*w[n];
            else if (n < 544){ int i=n-512; o = vals[512+2*i]*cosb[b*32+i] - vals[513+2*i]*sinb[b*32+i]; }
            else            { int i=n-544; o = vals[513+2*i]*cosb[b*32+i] + vals[512+2*i]*sinb[b*32+i]; }
            latent[(size_t)b*576 + n] = o;
        }
    }
}

// ---------- ql_nope: query[b][h][r] = sum_n q[b][h][n]*w_uk_t[h][n][r]   (r<512)
__global__ __launch_bounds__(256) void qlnope_query(const float* __restrict__ q,
        const float* __restrict__ wukt, float* __restrict__ query)
{
    const int h = blockIdx.x;
    const int t = threadIdx.x;
    const int r = blockIdx.y*256 + t;
    __shared__ float qn[64*128];
    float acc[64];
#pragma unroll
    for (int i=0;i<64;++i) acc[i]=0.f;
#pragma unroll
    for (int i=0;i<32;++i){
        int idx = i*256+t;
        int bb = idx>>7, nn = idx&127;
        qn[idx] = q[((size_t)bb*32+h)*192 + nn];
    }
    __syncthreads();
    const float* wp = wukt + (size_t)h*128*512 + r;
    for (int n0=0;n0<128;n0+=4){
        float w0 = wp[(size_t)(n0+0)*512];
        float w1 = wp[(size_t)(n0+1)*512];
        float w2 = wp[(size_t)(n0+2)*512];
        float w3 = wp[(size_t)(n0+3)*512];
#pragma unroll
        for (int bb=0;bb<64;++bb){
            const float4 a = *(const float4*)(qn + bb*128 + n0);
            acc[bb] = fmaf(a.x,w0,fmaf(a.y,w1,fmaf(a.z,w2,fmaf(a.w,w3,acc[bb]))));
        }
    }
#pragma unroll
    for (int bb=0;bb<64;++bb) query[((size_t)bb*32+h)*576 + r] = acc[bb];
}

// ---------- rope for q_pe -> query[b][h][512..575]
__global__ __launch_bounds__(256) void rope_q(const float* __restrict__ q,
        const float* __restrict__ cosb, const float* __restrict__ sinb, float* __restrict__ query)
{
    const int b = blockIdx.x, t = threadIdx.x;
#pragma unroll
    for (int j=0;j<4;++j){
        int item = j*256+t;
        int h = item>>5, i = item&31;
        const float* qp = q + ((size_t)b*32+h)*192 + 128;
        float x1 = qp[2*i], x2 = qp[2*i+1];
        float c = cosb[b*32+i], s = sinb[b*32+i];
        float* o = query + ((size_t)b*32+h)*576;
        o[512+i] = x1*c - x2*s;
        o[544+i] = x2*c + x1*s;
    }
}

// ---------- flash decode attention, bf16 MFMA 16x16x32
// v2: top-of-loop prefetch (real overlap), in-register 8x8 transpose (vector LDS only)
__global__ __launch_bounds__(256,2) void attn_mfma(const float* __restrict__ query,
        const float* __restrict__ kv, const float* __restrict__ latent,
        const int* __restrict__ slots, const int* __restrict__ seq_lens,
        float* __restrict__ Opart, float* __restrict__ Mpart, float* __restrict__ Lpart)
{
    __shared__ unsigned short Krows[32*576];
    __shared__ unsigned short Vt[512*32];
    __shared__ float S_s[32*33];
    __shared__ unsigned short P_s[32*40];
    __shared__ float alpha_s[32];

    const int b = blockIdx.y, sp = blockIdx.x;
    const int tid = threadIdx.x;
    const int w = tid>>6, l = tid&63;
    const int lm = l&15, lg = l>>4;
    const int ht = w&1, kt = w>>1;
    const int seqlen = seq_lens[b];
    const int slot = slots[b];
    const int k0 = sp*512;
    const int myh = tid>>3, s5 = tid&7;

    bf16x8 qf[18];
    {
        const float* qrow = query + ((size_t)b*32 + ht*16 + lm)*576;
#pragma unroll
        for (int s=0;s<18;++s){
            int d0 = s*32 + lg*8;
            float4 a = *(const float4*)(qrow + d0);
            float4 c = *(const float4*)(qrow + d0 + 4);
            union{uint4 u; bf16x8 v;} cv;
            cv.u.x=pack2(a.x,a.y); cv.u.y=pack2(a.z,a.w);
            cv.u.z=pack2(c.x,c.y); cv.u.w=pack2(c.z,c.w);
            qf[s]=cv.v;
        }
    }

    float4 ld[18];
    auto load_tile = [&](int tt){
#pragma unroll
        for (int c=0;c<9;++c){
            int off = c*2048 + tid*8;
            int row = off/576, col = off - row*576;
            int gk = k0 + tt*32 + row;
            const float* src = (gk==slot) ? (latent + (size_t)b*576 + col)
                                          : (kv + ((size_t)b*KCTX + gk)*576 + col);
            ld[2*c]   = *(const float4*)src;
            ld[2*c+1] = *(const float4*)(src+4);
        }
    };
    auto write_tile = [&](){
#pragma unroll
        for (int c=0;c<9;++c){
            int off = c*2048 + tid*8;
            int row = off/576, col = off - row*576;
            float4 a = ld[2*c], d = ld[2*c+1];
            uint4 u;
            u.x=pack2(a.x,a.y); u.y=pack2(a.z,a.w);
            u.z=pack2(d.x,d.y); u.w=pack2(d.z,d.w);
            *(uint4*)(Krows + row*576 + (col ^ ((row&7)<<3))) = u;
        }
    };

    f32x4 oacc[16];
#pragma unroll
    for (int i=0;i<16;++i){ oacc[i][0]=0.f; oacc[i][1]=0.f; oacc[i][2]=0.f; oacc[i][3]=0.f; }
    float m_run = NEGINF, l_run = 0.f;

    load_tile(0); write_tile(); __syncthreads();

    for (int tt=0; tt<16; ++tt){
        if (tt < 15) load_tile(tt+1);   // issue prefetch early; drained at barrier #1

        // ---- in-register 8x8 transpose: Krows(d<512) -> Vt[d][key], slot g^( (d>>3)&3 )
        {
            const int kq = w*8;       // this thread's 8 keys
            const int d0 = l*8;       // this thread's 8 d-values (0..511)
            unsigned rw[8][4];
#pragma unroll
            for (int i=0;i<8;++i){
                int r = kq + i;
                uint4 rv = *(const uint4*)(Krows + r*576 + (d0 ^ ((r&7)<<3)));
                rw[i][0]=rv.x; rw[i][1]=rv.y; rw[i][2]=rv.z; rw[i][3]=rv.w;
            }
            const int slotb = (w ^ (l&3))<<3;
#pragma unroll
            for (int j=0;j<8;++j){
                const int sel = j>>1;
                uint4 o;
                if (j&1){
                    o.x = (rw[0][sel]>>16) | (rw[1][sel]&0xffff0000u);
                    o.y = (rw[2][sel]>>16) | (rw[3][sel]&0xffff0000u);
                    o.z = (rw[4][sel]>>16) | (rw[5][sel]&0xffff0000u);
                    o.w = (rw[6][sel]>>16) | (rw[7][sel]&0xffff0000u);
                } else {
                    o.x = (rw[0][sel]&0xffffu) | (rw[1][sel]<<16);
                    o.y = (rw[2][sel]&0xffffu) | (rw[3][sel]<<16);
                    o.z = (rw[4][sel]&0xffffu) | (rw[5][sel]<<16);
                    o.w = (rw[6][sel]&0xffffu) | (rw[7][sel]<<16);
                }
                *(uint4*)(Vt + (d0+j)*32 + slotb) = o;
            }
        }
        // ---- QK^T
        {
            f32x4 sacc; sacc[0]=0.f; sacc[1]=0.f; sacc[2]=0.f; sacc[3]=0.f;
            const int key = kt*16 + lm;
            const unsigned short* kb = Krows + key*576;
            const int sw = (key&7)<<3;
#pragma unroll
            for (int s=0;s<18;++s){
                int dof = s*32 + lg*8;
                bf16x8 bv = *(const bf16x8*)(kb + (dof ^ sw));
                sacc = __builtin_amdgcn_mfma_f32_16x16x32_bf16(qf[s], bv, sacc, 0,0,0);
            }
            int hrow = ht*16 + (lg<<2);
#pragma unroll
            for (int r=0;r<4;++r) S_s[(hrow+r)*33 + key] = sacc[r];
        }
        __syncthreads();

        // ---- online softmax
        {
            const int kbase = k0 + tt*32;
            float sc[4];
#pragma unroll
            for (int j=0;j<4;++j){
                int k = s5 + 8*j;
                float v = S_s[myh*33 + k]*SM_SCALE;
                sc[j] = (kbase + k < seqlen) ? v : NEGINF;
            }
            float tmax = fmaxf(fmaxf(sc[0],sc[1]),fmaxf(sc[2],sc[3]));
            tmax = fmaxf(tmax, __shfl_xor(tmax,1));
            tmax = fmaxf(tmax, __shfl_xor(tmax,2));
            tmax = fmaxf(tmax, __shfl_xor(tmax,4));
            float mnew = fmaxf(m_run, tmax);
            float al = __expf(m_run - mnew);
            float ps = 0.f;
#pragma unroll
            for (int j=0;j<4;++j){
                float pv = (sc[j] > 0.5f*NEGINF) ? __expf(sc[j]-mnew) : 0.f;
                ps += pv;
                P_s[myh*40 + s5 + 8*j] = f2bf(pv);
            }
            ps += __shfl_xor(ps,1); ps += __shfl_xor(ps,2); ps += __shfl_xor(ps,4);
            l_run = l_run*al + ps;
            m_run = mnew;
            if (s5==0) alpha_s[myh] = al;
        }
        __syncthreads();

        // ---- PV
        {
            float al4[4];
#pragma unroll
            for (int r=0;r<4;++r) al4[r] = alpha_s[ht*16 + (lg<<2) + r];
            bf16x8 pa = *(const bf16x8*)(P_s + (ht*16+lm)*40 + lg*8);
#pragma unroll
            for (int nt=0;nt<16;++nt){
                f32x4 o = oacc[nt];
                o[0]*=al4[0]; o[1]*=al4[1]; o[2]*=al4[2]; o[3]*=al4[3];
                int r = kt*256 + nt*16 + lm;
                bf16x8 bv = *(const bf16x8*)(Vt + r*32 + ((lg ^ ((r>>3)&3))<<3));
                oacc[nt] = __builtin_amdgcn_mfma_f32_16x16x32_bf16(pa, bv, o, 0,0,0);
            }
        }
        if (tt < 15) write_tile();      // loads already complete (drained at barrier #1)
        __syncthreads();
    }

    // ---- write partials
    const int obase = (b*NSPLIT+sp)*32;
#pragma unroll
    for (int nt=0;nt<16;++nt){
        int r = kt*256 + nt*16 + lm;
#pragma unroll
        for (int q=0;q<4;++q){
            int h = ht*16 + (lg<<2) + q;
            Opart[((size_t)(obase+h))*512 + r] = oacc[nt][q];
        }
    }
    if (s5==0){ Mpart[obase+myh]=m_run; Lpart[obase+myh]=l_run; }
}

// ---------- merge NSPLIT flash partials -> attn[b][h][512]
__global__ __launch_bounds__(256) void merge_attn(const float* __restrict__ Opart,
        const float* __restrict__ Mpart, const float* __restrict__ Lpart, float* __restrict__ attn)
{
    const int bh = blockIdx.x;
    const int b = bh>>5, h = bh&31;
    const int t = threadIdx.x;
    float m[NSPLIT], lw[NSPLIT];
    float M = NEGINF;
#pragma unroll
    for (int s=0;s<NSPLIT;++s){ m[s] = Mpart[(b*NSPLIT+s)*32 + h]; M = fmaxf(M,m[s]); }
    float L = 0.f;
#pragma unroll
    for (int s=0;s<NSPLIT;++s){ lw[s] = __expf(m[s]-M); L += lw[s]*Lpart[(b*NSPLIT+s)*32+h]; }
    float inv = 1.f/L;
#pragma unroll
    for (int j=0;j<2;++j){
        int r = j*256+t;
        float o = 0.f;
#pragma unroll
        for (int s=0;s<NSPLIT;++s)
            o += lw[s]*Opart[((size_t)((b*NSPLIT+s)*32) + h)*512 + r];
        attn[((size_t)b*32+h)*512 + r] = o*inv;
    }
}

// ---------- out[b][h*128+v] = sum_r attn[b][h][r]*w_uv[h][r][v]
__global__ __launch_bounds__(128) void av_uv(const float* __restrict__ attn,
        const float* __restrict__ wuv, float* __restrict__ ao)
{
    const int h = blockIdx.x, bg = blockIdx.y, t = threadIdx.x;
    __shared__ float a_s[8*512];
#pragma unroll
    for (int i=0;i<32;++i){
        int idx = i*128+t;
        int bb = idx>>9, rr = idx&511;
        a_s[idx] = attn[((size_t)(bg*8+bb)*32 + h)*512 + rr];
    }
    __syncthreads();
    float acc[8];
#pragma unroll
    for (int i=0;i<8;++i) acc[i]=0.f;
    const float* wp = wuv + (size_t)h*512*128 + t;
    for (int r0=0;r0<512;r0+=4){
        float w0 = wp[(size_t)(r0+0)*128];
        float w1 = wp[(size_t)(r0+1)*128];
        float w2 = wp[(size_t)(r0+2)*128];
        float w3 = wp[(size_t)(r0+3)*128];
#pragma unroll
        for (int bb=0;bb<8;++bb){
            const float4 a = *(const float4*)(a_s + bb*512 + r0);
            acc[bb] = fmaf(a.x,w0,fmaf(a.y,w1,fmaf(a.z,w2,fmaf(a.w,w3,acc[bb]))));
        }
    }
#pragma unroll
    for (int bb=0;bb<8;++bb) ao[(size_t)(bg*8+bb)*4096 + h*128 + t] = acc[bb];
}

extern "C" void kernel_launch(void* const* d_in, const int* in_sizes, int n_in,
                              void* d_out, int out_size, void* d_ws, size_t ws_size,
                              hipStream_t stream)
{
    const float* hidden = (const float*)d_in[0];
    const float* cosb   = (const float*)d_in[1];
    const float* sinb   = (const float*)d_in[2];
    const float* kv     = (const float*)d_in[3];
    const float* w_q_a  = (const float*)d_in[4];
    const float* q_ln   = (const float*)d_in[5];
    const float* w_q_b  = (const float*)d_in[6];
    const float* w_kv_a = (const float*)d_in[7];
    const float* kv_ln  = (const float*)d_in[8];
    const float* w_uk_t = (const float*)d_in[9];
    const float* w_uv   = (const float*)d_in[10];
    const float* w_o    = (const float*)d_in[11];
    const int* slots    = (const int*)d_in[12];
    const int* seqlens  = (const int*)d_in[13];
    float* out = (float*)d_out;

    float* W = (float*)d_ws;
    float* P      = W;                  // partials; aliases Opart
    float* q_c    = W + 8388608;
    float* q      = W + 8486912;
    float* latent = W + 8880128;
    float* query  = W + 8916992;
    float* Mp     = W + 10096640;
    float* Lp     = W + 10113024;
    float* attn   = W + 10129408;
    float* ao     = W + 11177984;
    unsigned short* pkhid_h = (unsigned short*)(W + 11440128);   // 64*7168 bf16 = 229376 f32
    unsigned short* pkhid_l = (unsigned short*)(W + 11669504);
    unsigned short* pkqc_h  = (unsigned short*)(W + 11898880);   // 64*1536 bf16 = 49152 f32
    unsigned short* pkqc_l  = (unsigned short*)(W + 11948032);
    unsigned short* pkao_h  = (unsigned short*)(W + 11997184);   // 64*4096 bf16 = 131072 f32
    unsigned short* pkao_l  = (unsigned short*)(W + 12128256);

    // q branch
    hipLaunchKernelGGL(pack_a, dim3(224), dim3(256), 0, stream, hidden, pkhid_h, pkhid_l, 7168);
    hipLaunchKernelGGL(gemm_mfma, dim3(24,28), dim3(256), 0, stream, pkhid_h, pkhid_l, w_q_a, P, 1536, 8);
    hipLaunchKernelGGL(reduce_rms_qc, dim3(64), dim3(256), 0, stream, P, q_ln, q_c, 28);
    hipLaunchKernelGGL(pack_a, dim3(48), dim3(256), 0, stream, q_c, pkqc_h, pkqc_l, 1536);
    hipLaunchKernelGGL(gemm_mfma, dim3(96,6), dim3(256), 0, stream, pkqc_h, pkqc_l, w_q_b, P, 6144, 8);
    hipLaunchKernelGGL(reduce_sum, dim3(1536), dim3(256), 0, stream, P, q, 6, 6144);
    // kv branch
    hipLaunchKernelGGL(gemm_mfma, dim3(9,56), dim3(256), 0, stream, pkhid_h, pkhid_l, w_kv_a, P, 576, 4);
    hipLaunchKernelGGL(reduce_kv_rope, dim3(64), dim3(256), 0, stream, P, kv_ln, cosb, sinb, latent, 56);
    // query assembly
    hipLaunchKernelGGL(qlnope_query, dim3(32,2), dim3(256), 0, stream, q, w_uk_t, query);
    hipLaunchKernelGGL(rope_q, dim3(64), dim3(256), 0, stream, q, cosb, sinb, query);
    // attention
    hipLaunchKernelGGL(attn_mfma, dim3(NSPLIT,64), dim3(256), 0, stream,
                       query, kv, latent, slots, seqlens, P, Mp, Lp);
    hipLaunchKernelGGL(merge_attn, dim3(2048), dim3(256), 0, stream, P, Mp, Lp, attn);
    hipLaunchKernelGGL(av_uv, dim3(32,8), dim3(128), 0, stream, attn, w_uv, ao);
    // output projection
    hipLaunchKernelGGL(pack_a, dim3(128), dim3(256), 0, stream, ao, pkao_h, pkao_l, 4096);
    hipLaunchKernelGGL(gemm_mfma, dim3(112,8), dim3(256), 0, stream, pkao_h, pkao_l, w_o, P, 7168, 16);
    hipLaunchKernelGGL(reduce_sum, dim3(1792), dim3(256), 0, stream, P, out, 8, 7168);
}

// Round 6
// 624.039 us; speedup vs baseline: 1.0808x; 1.0808x over previous
//
#include <hip/hip_runtime.h>
#include <stdint.h>

#define NB 64
#define NH 32
#define KCTX 4096
#define HID 7168
#define QLORA 1536
#define KVL 512
#define DTOT 576
#define NSPLIT 12
#define KSPAN 352
#define NTILE 22           // KSPAN/16
#define TK 16
#define SM_SCALE 0.07216878364870323f  // 1/sqrt(192)
#define NEGINF (-3.0e38f)

typedef __attribute__((ext_vector_type(4))) float f32x4;
typedef __attribute__((ext_vector_type(8))) __bf16 bf16x8;

static __device__ __forceinline__ unsigned short f2bf(float f){
    union{__bf16 h; unsigned short s;} x; x.h = (__bf16)f; return x.s;
}
static __device__ __forceinline__ float bf2f(unsigned short h){
    union{unsigned i;float f;}x; x.i=((unsigned)h)<<16; return x.f;
}
static __device__ __forceinline__ unsigned pack2(float a, float b){
    union{__bf16 h[2]; unsigned u;} x; x.h[0]=(__bf16)a; x.h[1]=(__bf16)b; return x.u;
}

// ---------- pack A[64][K] fp32 -> frag-ready bf16 hi/lo words: word idx = (k>>3)*64+m
__global__ __launch_bounds__(256) void pack_a(const float* __restrict__ A,
        unsigned short* __restrict__ Hi, unsigned short* __restrict__ Lo, int K)
{
    int idx = blockIdx.x*256 + threadIdx.x;
    int m = idx & 63, kb = idx >> 6;
    const float* src = A + (size_t)m*K + kb*8;
    float v[8];
    *(float4*)(v)   = *(const float4*)(src);
    *(float4*)(v+4) = *(const float4*)(src+4);
    unsigned short h[8], l[8];
#pragma unroll
    for (int j=0;j<8;++j){
        h[j] = f2bf(v[j]);
        l[j] = f2bf(v[j] - bf2f(h[j]));
    }
    uint4 uh, ul;
    uh.x=(unsigned)h[0]|((unsigned)h[1]<<16); uh.y=(unsigned)h[2]|((unsigned)h[3]<<16);
    uh.z=(unsigned)h[4]|((unsigned)h[5]<<16); uh.w=(unsigned)h[6]|((unsigned)h[7]<<16);
    ul.x=(unsigned)l[0]|((unsigned)l[1]<<16); ul.y=(unsigned)l[2]|((unsigned)l[3]<<16);
    ul.z=(unsigned)l[4]|((unsigned)l[5]<<16); ul.w=(unsigned)l[6]|((unsigned)l[7]<<16);
    *(uint4*)(Hi + (size_t)idx*8) = uh;
    *(uint4*)(Lo + (size_t)idx*8) = ul;
}

// ---------- MFMA skinny GEMM, double-buffered LDS, 1 barrier/step
__global__ __launch_bounds__(256) void gemm_mfma(
        const unsigned short* __restrict__ Ahi, const unsigned short* __restrict__ Alo,
        const float* __restrict__ Wm, float* __restrict__ P, int N, int ksteps)
{
    __shared__ unsigned short Ah[2][2048], Al[2][2048], Bh[2][2048], Bl[2][2048];
    const int tid = threadIdx.x;
    const int w = tid>>6, l = tid&63, lm = l&15, lg = l>>4;
    const int n0 = blockIdx.x*64;
    const int s  = blockIdx.y;
    const int mn = tid&63, ks = tid>>6;
    const int widx = ((mn>>4)*64 + ks*16 + (mn&15));

    f32x4 acc[4];
#pragma unroll
    for (int i=0;i<4;++i){ acc[i][0]=0.f; acc[i][1]=0.f; acc[i][2]=0.f; acc[i][3]=0.f; }

    uint4 ah4, al4; float wv[8];
    auto load_raw = [&](int t){
        const int k0 = (s*ksteps + t)*32;
        size_t gidx = (size_t)((k0>>3) + ks)*64 + mn;
        ah4 = *(const uint4*)(Ahi + gidx*8);
        al4 = *(const uint4*)(Alo + gidx*8);
        const float* wp = Wm + (size_t)(k0 + ks*8)*N + n0 + mn;
#pragma unroll
        for (int j=0;j<8;++j) wv[j] = wp[(size_t)j*N];
    };
    auto cvt_write = [&](int buf){
        unsigned short h[8], lo[8];
#pragma unroll
        for (int j=0;j<8;++j){
            h[j]  = f2bf(wv[j]);
            lo[j] = f2bf(wv[j] - bf2f(h[j]));
        }
        uint4 bh4, bl4;
        bh4.x=(unsigned)h[0]|((unsigned)h[1]<<16); bh4.y=(unsigned)h[2]|((unsigned)h[3]<<16);
        bh4.z=(unsigned)h[4]|((unsigned)h[5]<<16); bh4.w=(unsigned)h[6]|((unsigned)h[7]<<16);
        bl4.x=(unsigned)lo[0]|((unsigned)lo[1]<<16); bl4.y=(unsigned)lo[2]|((unsigned)lo[3]<<16);
        bl4.z=(unsigned)lo[4]|((unsigned)lo[5]<<16); bl4.w=(unsigned)lo[6]|((unsigned)lo[7]<<16);
        *(uint4*)(&Ah[buf][widx*8]) = ah4;
        *(uint4*)(&Al[buf][widx*8]) = al4;
        *(uint4*)(&Bh[buf][widx*8]) = bh4;
        *(uint4*)(&Bl[buf][widx*8]) = bl4;
    };

    load_raw(0);
    for (int t=0; t<ksteps; ++t){
        const int buf = t&1;
        cvt_write(buf);
        __syncthreads();
        if (t+1 < ksteps) load_raw(t+1);
        const int fa = (w*64 + lg*16 + lm)*8;
        bf16x8 fah = *(const bf16x8*)(&Ah[buf][fa]);
        bf16x8 fal = *(const bf16x8*)(&Al[buf][fa]);
#pragma unroll
        for (int nt=0;nt<4;++nt){
            const int fb = (nt*64 + lg*16 + lm)*8;
            bf16x8 fbh = *(const bf16x8*)(&Bh[buf][fb]);
            bf16x8 fbl = *(const bf16x8*)(&Bl[buf][fb]);
            acc[nt] = __builtin_amdgcn_mfma_f32_16x16x32_bf16(fah, fbh, acc[nt], 0,0,0);
            acc[nt] = __builtin_amdgcn_mfma_f32_16x16x32_bf16(fal, fbh, acc[nt], 0,0,0);
            acc[nt] = __builtin_amdgcn_mfma_f32_16x16x32_bf16(fah, fbl, acc[nt], 0,0,0);
        }
    }
#pragma unroll
    for (int nt=0;nt<4;++nt){
        int n = n0 + nt*16 + lm;
#pragma unroll
        for (int r=0;r<4;++r){
            int m = w*16 + lg*4 + r;
            P[((size_t)s*64 + m)*N + n] = acc[nt][r];
        }
    }
}

// ---------- reduce S partials + rmsnorm -> q_c[64][1536]
__global__ __launch_bounds__(256) void reduce_rms_qc(const float* __restrict__ P,
        const float* __restrict__ w, float* __restrict__ out, int S)
{
    const int b = blockIdx.x, t = threadIdx.x;
    float v[6]; float ss = 0.f;
#pragma unroll
    for (int j=0;j<6;++j){
        int n = j*256 + t;
        float s = 0.f;
        for (int sp=0; sp<S; ++sp) s += P[((size_t)sp*64+b)*1536 + n];
        v[j] = s; ss += s*s;
    }
    __shared__ float red[4];
#pragma unroll
    for (int off=32; off>=1; off>>=1) ss += __shfl_xor(ss, off, 64);
    if ((t&63)==0) red[t>>6] = ss;
    __syncthreads();
    float tot = red[0]+red[1]+red[2]+red[3];
    float rs = rsqrtf(tot/1536.f + 1e-6f);
#pragma unroll
    for (int j=0;j<6;++j){
        int n = j*256+t;
        out[(size_t)b*1536 + n] = v[j]*rs*w[n];
    }
}

// ---------- generic partial reduce
__global__ __launch_bounds__(256) void reduce_sum(const float* __restrict__ P,
        float* __restrict__ out, int S, int N)
{
    int i = blockIdx.x*256 + threadIdx.x;
    int b = i / N, n = i - b*N;
    float s = 0.f;
    for (int sp=0; sp<S; ++sp) s += P[((size_t)sp*64+b)*N + n];
    out[i] = s;
}

// ---------- reduce ckv partials + rmsnorm(512) + rope(last 64) -> latent[64][576]
__global__ __launch_bounds__(256) void reduce_kv_rope(const float* __restrict__ P,
        const float* __restrict__ w, const float* __restrict__ cosb, const float* __restrict__ sinb,
        float* __restrict__ latent, int S)
{
    const int b = blockIdx.x, t = threadIdx.x;
    __shared__ float vals[576];
    __shared__ float red[4];
    float ss = 0.f;
    for (int j=0;j<3;++j){
        int n = j*256+t;
        if (n < 576){
            float s=0.f;
            for (int sp=0;sp<S;++sp) s += P[((size_t)sp*64+b)*576 + n];
            vals[n]=s;
            if (n<512) ss += s*s;
        }
    }
#pragma unroll
    for (int off=32; off>=1; off>>=1) ss += __shfl_xor(ss, off, 64);
    if ((t&63)==0) red[t>>6]=ss;
    __syncthreads();
    float tot = red[0]+red[1]+red[2]+red[3];
    float rs = rsqrtf(tot/512.f + 1e-6f);
    for (int j=0;j<3;++j){
        int n = j*256+t;
        if (n<576){
            float o;
            if (n < 512) o = vals[n]*rs*w[n];
            else if (n < 544){ int i=n-512; o = vals[512+2*i]*cosb[b*32+i] - vals[513+2*i]*sinb[b*32+i]; }
            else            { int i=n-544; o = vals[513+2*i]*cosb[b*32+i] + vals[512+2*i]*sinb[b*32+i]; }
            latent[(size_t)b*576 + n] = o;
        }
    }
}

// ---------- ql_nope: query[b][h][r] = sum_n q[b][h][n]*w_uk_t[h][n][r]   (r<512)
__global__ __launch_bounds__(256) void qlnope_query(const float* __restrict__ q,
        const float* __restrict__ wukt, float* __restrict__ query)
{
    const int h = blockIdx.x;
    const int t = threadIdx.x;
    const int r = blockIdx.y*256 + t;
    __shared__ float qn[64*128];
    float acc[64];
#pragma unroll
    for (int i=0;i<64;++i) acc[i]=0.f;
#pragma unroll
    for (int i=0;i<32;++i){
        int idx = i*256+t;
        int bb = idx>>7, nn = idx&127;
        qn[idx] = q[((size_t)bb*32+h)*192 + nn];
    }
    __syncthreads();
    const float* wp = wukt + (size_t)h*128*512 + r;
    for (int n0=0;n0<128;n0+=4){
        float w0 = wp[(size_t)(n0+0)*512];
        float w1 = wp[(size_t)(n0+1)*512];
        float w2 = wp[(size_t)(n0+2)*512];
        float w3 = wp[(size_t)(n0+3)*512];
#pragma unroll
        for (int bb=0;bb<64;++bb){
            const float4 a = *(const float4*)(qn + bb*128 + n0);
            acc[bb] = fmaf(a.x,w0,fmaf(a.y,w1,fmaf(a.z,w2,fmaf(a.w,w3,acc[bb]))));
        }
    }
#pragma unroll
    for (int bb=0;bb<64;++bb) query[((size_t)bb*32+h)*576 + r] = acc[bb];
}

// ---------- rope for q_pe -> query[b][h][512..575]
__global__ __launch_bounds__(256) void rope_q(const float* __restrict__ q,
        const float* __restrict__ cosb, const float* __restrict__ sinb, float* __restrict__ query)
{
    const int b = blockIdx.x, t = threadIdx.x;
#pragma unroll
    for (int j=0;j<4;++j){
        int item = j*256+t;
        int h = item>>5, i = item&31;
        const float* qp = q + ((size_t)b*32+h)*192 + 128;
        float x1 = qp[2*i], x2 = qp[2*i+1];
        float c = cosb[b*32+i], s = sinb[b*32+i];
        float* o = query + ((size_t)b*32+h)*576;
        o[512+i] = x1*c - x2*s;
        o[544+i] = x2*c + x1*s;
    }
}

// Vt flat layout: addr_u16(d,key) = (d>>2)*64 + ((d&3)^((d>>3)&3))*16 + key
static __device__ __forceinline__ int vt_addr(int d, int key){
    return (d>>2)*64 + (((d&3)^((d>>3)&3))<<4) + key;
}

// ---------- flash decode attention v3: TK=16, 3 blocks/CU, d-split Q, zero-pad PV
__global__ __launch_bounds__(256,3) void attn_mfma(const float* __restrict__ query,
        const float* __restrict__ kv, const float* __restrict__ latent,
        const int* __restrict__ slots, const int* __restrict__ seq_lens,
        float* __restrict__ Opart, float* __restrict__ Mpart, float* __restrict__ Lpart)
{
    __shared__ unsigned short Krows[TK*576];      // 18432 B, XOR swizzle (row&7)<<3
    __shared__ unsigned short Vt[8192];           // 16384 B, windowed layout
    __shared__ float S_s[2][32][16];              // 4096 B, two d-half partials
    __shared__ unsigned short P_s[32][40];        // 2560 B, keys 16..31 zeroed
    __shared__ float alpha_s[32];

    const int b = blockIdx.y, sp = blockIdx.x;
    const int tid = threadIdx.x;
    const int w = tid>>6, l = tid&63;
    const int lm = l&15, lg = l>>4;
    const int ht = w&1;                 // h-tile
    const int dh = w>>1;                // QK d-half / PV r-half
    const int seqlen = seq_lens[b];
    const int slot = slots[b];
    const int k0 = sp*KSPAN;
    const int myh = tid>>3, s5 = tid&7;

    // zero the pad region of P_s (keys 16..31)
    {
        int id = tid*2;
        P_s[id>>4][16 + (id&15)] = 0;
        id++;
        P_s[id>>4][16 + (id&15)] = 0;
    }

    // Q fragments: 9 d-chunks of this wave's d-half
    bf16x8 qf[9];
    {
        const float* qrow = query + ((size_t)b*32 + ht*16 + lm)*576;
#pragma unroll
        for (int ss=0;ss<9;++ss){
            int d0 = (dh*9+ss)*32 + lg*8;
            float4 a = *(const float4*)(qrow + d0);
            float4 c = *(const float4*)(qrow + d0 + 4);
            union{uint4 u; bf16x8 v;} cv;
            cv.u.x=pack2(a.x,a.y); cv.u.y=pack2(a.z,a.w);
            cv.u.z=pack2(c.x,c.y); cv.u.w=pack2(c.z,c.w);
            qf[ss]=cv.v;
        }
    }

    // staging: 16x576 fp32 tile -> Krows bf16 swizzled. 9 float4/thread.
    auto stage_tile = [&](int tt){
        float4 ld[9];
#pragma unroll
        for (int c=0;c<9;++c){
            int idx = c*256 + tid;
            int row = idx/144, col = (idx - row*144)*4;
            int gk = k0 + tt*TK + row;
            if (gk > KCTX-1) gk = KCTX-1;
            const float* src = (gk==slot) ? (latent + (size_t)b*576 + col)
                                          : (kv + ((size_t)b*KCTX + gk)*576 + col);
            ld[c] = *(const float4*)src;
        }
#pragma unroll
        for (int c=0;c<9;++c){
            int idx = c*256 + tid;
            int row = idx/144, col = (idx - row*144)*4;
            unsigned lo = pack2(ld[c].x, ld[c].y);
            unsigned hi = pack2(ld[c].z, ld[c].w);
            uint2 u; u.x=lo; u.y=hi;
            *(uint2*)(Krows + row*576 + (col ^ ((row&7)<<3))) = u;
        }
    };

    f32x4 oacc[16];
#pragma unroll
    for (int i=0;i<16;++i){ oacc[i][0]=0.f; oacc[i][1]=0.f; oacc[i][2]=0.f; oacc[i][3]=0.f; }
    float m_run = NEGINF, l_run = 0.f;

    stage_tile(0);
    __syncthreads();

    for (int tt=0; tt<NTILE; ++tt){
        // ---- transpose Krows(d<512) -> Vt. thread: kg=tid&1 (8 keys), d0=(tid>>1)*4
        {
            const int kg = tid&1;
            const int d0 = (tid>>1)*4;
            uint2 rw[8];
#pragma unroll
            for (int i=0;i<8;++i){
                int row = kg*8 + i;
                rw[i] = *(const uint2*)(Krows + row*576 + (d0 ^ ((row&7)<<3)));
            }
#pragma unroll
            for (int j=0;j<4;++j){
                const int sel = j>>1, sh = (j&1)*16;
                unsigned t0 = (rw[0].x >> 0, 0u), dummy=0; (void)t0; (void)dummy;
                unsigned e0 = ((sel? rw[0].y : rw[0].x) >> sh) & 0xffffu;
                unsigned e1 = ((sel? rw[1].y : rw[1].x) >> sh) & 0xffffu;
                unsigned e2 = ((sel? rw[2].y : rw[2].x) >> sh) & 0xffffu;
                unsigned e3 = ((sel? rw[3].y : rw[3].x) >> sh) & 0xffffu;
                unsigned e4 = ((sel? rw[4].y : rw[4].x) >> sh) & 0xffffu;
                unsigned e5 = ((sel? rw[5].y : rw[5].x) >> sh) & 0xffffu;
                unsigned e6 = ((sel? rw[6].y : rw[6].x) >> sh) & 0xffffu;
                unsigned e7 = ((sel? rw[7].y : rw[7].x) >> sh) & 0xffffu;
                uint4 o;
                o.x = e0 | (e1<<16); o.y = e2 | (e3<<16);
                o.z = e4 | (e5<<16); o.w = e6 | (e7<<16);
                *(uint4*)(Vt + vt_addr(d0+j, kg*8)) = o;
            }
        }
        // ---- QK^T partial (this wave's d-half): one 16x16 output tile
        {
            f32x4 sacc; sacc[0]=0.f; sacc[1]=0.f; sacc[2]=0.f; sacc[3]=0.f;
            const unsigned short* kb = Krows + lm*576;   // key = lm
            const int sw = (lm&7)<<3;
#pragma unroll
            for (int ss=0;ss<9;++ss){
                int dof = (dh*9+ss)*32 + lg*8;
                bf16x8 bv = *(const bf16x8*)(kb + (dof ^ sw));
                sacc = __builtin_amdgcn_mfma_f32_16x16x32_bf16(qf[ss], bv, sacc, 0,0,0);
            }
#pragma unroll
            for (int r=0;r<4;++r) S_s[dh][ht*16 + (lg<<2) + r][lm] = sacc[r];
        }
        __syncthreads();

        // ---- online softmax: 8 threads/head, 2 keys each
        {
            const int kbase = k0 + tt*TK;
            float sc[2];
#pragma unroll
            for (int j=0;j<2;++j){
                int k = s5 + 8*j;
                float v = (S_s[0][myh][k] + S_s[1][myh][k])*SM_SCALE;
                sc[j] = (kbase + k < seqlen) ? v : NEGINF;
            }
            float tmax = fmaxf(sc[0],sc[1]);
            tmax = fmaxf(tmax, __shfl_xor(tmax,1));
            tmax = fmaxf(tmax, __shfl_xor(tmax,2));
            tmax = fmaxf(tmax, __shfl_xor(tmax,4));
            float mnew = fmaxf(m_run, tmax);
            float al = __expf(m_run - mnew);
            float ps = 0.f;
#pragma unroll
            for (int j=0;j<2;++j){
                float pv = (sc[j] > 0.5f*NEGINF) ? __expf(sc[j]-mnew) : 0.f;
                ps += pv;
                P_s[myh][s5 + 8*j] = f2bf(pv);
            }
            ps += __shfl_xor(ps,1); ps += __shfl_xor(ps,2); ps += __shfl_xor(ps,4);
            l_run = l_run*al + ps;
            m_run = mnew;
            if (s5==0) alpha_s[myh] = al;
        }
        __syncthreads();

        // ---- PV: wave owns h-tile ht, r-range dh*256; K=32 mfma with zero-padded P
        {
            float al4[4];
#pragma unroll
            for (int r=0;r<4;++r) al4[r] = alpha_s[ht*16 + (lg<<2) + r];
            bf16x8 pa = *(const bf16x8*)(&P_s[ht*16+lm][lg*8]);
#pragma unroll
            for (int nt=0;nt<16;++nt){
                f32x4 o = oacc[nt];
                o[0]*=al4[0]; o[1]*=al4[1]; o[2]*=al4[2]; o[3]*=al4[3];
                int r = dh*256 + nt*16 + lm;
                bf16x8 bv = *(const bf16x8*)(Vt + vt_addr(r, (lg&1)*8));
                oacc[nt] = __builtin_amdgcn_mfma_f32_16x16x32_bf16(pa, bv, o, 0,0,0);
            }
        }
        if (tt+1 < NTILE) stage_tile(tt+1);   // load+convert+write, bounded lifetime
        __syncthreads();
    }

    // ---- write partials
    const int obase = (b*NSPLIT+sp)*32;
#pragma unroll
    for (int nt=0;nt<16;++nt){
        int r = dh*256 + nt*16 + lm;
#pragma unroll
        for (int q=0;q<4;++q){
            int h = ht*16 + (lg<<2) + q;
            Opart[((size_t)(obase+h))*512 + r] = oacc[nt][q];
        }
    }
    if (s5==0){ Mpart[obase+myh]=m_run; Lpart[obase+myh]=l_run; }
}

// ---------- merge NSPLIT flash partials -> attn[b][h][512]
__global__ __launch_bounds__(256) void merge_attn(const float* __restrict__ Opart,
        const float* __restrict__ Mpart, const float* __restrict__ Lpart, float* __restrict__ attn)
{
    const int bh = blockIdx.x;
    const int b = bh>>5, h = bh&31;
    const int t = threadIdx.x;
    float m[NSPLIT], lw[NSPLIT];
    float M = NEGINF;
#pragma unroll
    for (int s=0;s<NSPLIT;++s){ m[s] = Mpart[(b*NSPLIT+s)*32 + h]; M = fmaxf(M,m[s]); }
    float L = 0.f;
#pragma unroll
    for (int s=0;s<NSPLIT;++s){ lw[s] = __expf(m[s]-M); L += lw[s]*Lpart[(b*NSPLIT+s)*32+h]; }
    float inv = 1.f/L;
#pragma unroll
    for (int j=0;j<2;++j){
        int r = j*256+t;
        float o = 0.f;
#pragma unroll
        for (int s=0;s<NSPLIT;++s)
            o += lw[s]*Opart[((size_t)((b*NSPLIT+s)*32) + h)*512 + r];
        attn[((size_t)b*32+h)*512 + r] = o*inv;
    }
}

// ---------- out[b][h*128+v] = sum_r attn[b][h][r]*w_uv[h][r][v]
__global__ __launch_bounds__(128) void av_uv(const float* __restrict__ attn,
        const float* __restrict__ wuv, float* __restrict__ ao)
{
    const int h = blockIdx.x, bg = blockIdx.y, t = threadIdx.x;
    __shared__ float a_s[8*512];
#pragma unroll
    for (int i=0;i<32;++i){
        int idx = i*128+t;
        int bb = idx>>9, rr = idx&511;
        a_s[idx] = attn[((size_t)(bg*8+bb)*32 + h)*512 + rr];
    }
    __syncthreads();
    float acc[8];
#pragma unroll
    for (int i=0;i<8;++i) acc[i]=0.f;
    const float* wp = wuv + (size_t)h*512*128 + t;
    for (int r0=0;r0<512;r0+=4){
        float w0 = wp[(size_t)(r0+0)*128];
        float w1 = wp[(size_t)(r0+1)*128];
        float w2 = wp[(size_t)(r0+2)*128];
        float w3 = wp[(size_t)(r0+3)*128];
#pragma unroll
        for (int bb=0;bb<8;++bb){
            const float4 a = *(const float4*)(a_s + bb*512 + r0);
            acc[bb] = fmaf(a.x,w0,fmaf(a.y,w1,fmaf(a.z,w2,fmaf(a.w,w3,acc[bb]))));
        }
    }
#pragma unroll
    for (int bb=0;bb<8;++bb) ao[(size_t)(bg*8+bb)*4096 + h*128 + t] = acc[bb];
}

extern "C" void kernel_launch(void* const* d_in, const int* in_sizes, int n_in,
                              void* d_out, int out_size, void* d_ws, size_t ws_size,
                              hipStream_t stream)
{
    const float* hidden = (const float*)d_in[0];
    const float* cosb   = (const float*)d_in[1];
    const float* sinb   = (const float*)d_in[2];
    const float* kv     = (const float*)d_in[3];
    const float* w_q_a  = (const float*)d_in[4];
    const float* q_ln   = (const float*)d_in[5];
    const float* w_q_b  = (const float*)d_in[6];
    const float* w_kv_a = (const float*)d_in[7];
    const float* kv_ln  = (const float*)d_in[8];
    const float* w_uk_t = (const float*)d_in[9];
    const float* w_uv   = (const float*)d_in[10];
    const float* w_o    = (const float*)d_in[11];
    const int* slots    = (const int*)d_in[12];
    const int* seqlens  = (const int*)d_in[13];
    float* out = (float*)d_out;

    float* W = (float*)d_ws;
    float* P      = W;                   // partials / Opart: needs 12*64*32*512 = 12.58M f32
    float* q_c    = W + 12582912;
    float* q      = W + 12681216;
    float* latent = W + 13074432;
    float* query  = W + 13111296;
    float* Mp     = W + 14290944;
    float* Lp     = W + 14323712;
    float* attn   = W + 14356480;
    float* ao     = W + 15405056;
    unsigned short* pkhid_h = (unsigned short*)(W + 15667200);
    unsigned short* pkhid_l = (unsigned short*)(W + 15896576);
    unsigned short* pkqc_h  = (unsigned short*)(W + 16125952);
    unsigned short* pkqc_l  = (unsigned short*)(W + 16175104);
    unsigned short* pkao_h  = (unsigned short*)(W + 16224256);
    unsigned short* pkao_l  = (unsigned short*)(W + 16355328);

    // q branch
    hipLaunchKernelGGL(pack_a, dim3(224), dim3(256), 0, stream, hidden, pkhid_h, pkhid_l, 7168);
    hipLaunchKernelGGL(gemm_mfma, dim3(24,28), dim3(256), 0, stream, pkhid_h, pkhid_l, w_q_a, P, 1536, 8);
    hipLaunchKernelGGL(reduce_rms_qc, dim3(64), dim3(256), 0, stream, P, q_ln, q_c, 28);
    hipLaunchKernelGGL(pack_a, dim3(48), dim3(256), 0, stream, q_c, pkqc_h, pkqc_l, 1536);
    hipLaunchKernelGGL(gemm_mfma, dim3(96,6), dim3(256), 0, stream, pkqc_h, pkqc_l, w_q_b, P, 6144, 8);
    hipLaunchKernelGGL(reduce_sum, dim3(1536), dim3(256), 0, stream, P, q, 6, 6144);
    // kv branch
    hipLaunchKernelGGL(gemm_mfma, dim3(9,56), dim3(256), 0, stream, pkhid_h, pkhid_l, w_kv_a, P, 576, 4);
    hipLaunchKernelGGL(reduce_kv_rope, dim3(64), dim3(256), 0, stream, P, kv_ln, cosb, sinb, latent, 56);
    // query assembly
    hipLaunchKernelGGL(qlnope_query, dim3(32,2), dim3(256), 0, stream, q, w_uk_t, query);
    hipLaunchKernelGGL(rope_q, dim3(64), dim3(256), 0, stream, q, cosb, sinb, query);
    // attention
    hipLaunchKernelGGL(attn_mfma, dim3(NSPLIT,64), dim3(256), 0, stream,
                       query, kv, latent, slots, seqlens, P, Mp, Lp);
    hipLaunchKernelGGL(merge_attn, dim3(2048), dim3(256), 0, stream, P, Mp, Lp, attn);
    hipLaunchKernelGGL(av_uv, dim3(32,8), dim3(128), 0, stream, attn, w_uv, ao);
    // output projection
    hipLaunchKernelGGL(pack_a, dim3(128), dim3(256), 0, stream, ao, pkao_h, pkao_l, 4096);
    hipLaunchKernelGGL(gemm_mfma, dim3(112,8), dim3(256), 0, stream, pkao_h, pkao_l, w_o, P, 7168, 16);
    hipLaunchKernelGGL(reduce_sum, dim3(1792), dim3(256), 0, stream, P, out, 8, 7168);
}